// Round 1
// baseline (163.879 us; speedup 1.0000x reference)
//
#include <hip/hip_runtime.h>

#define SEQ 512
#define HID 768
#define P2  46
#define MT  64      // rows per block
#define KC  64      // K chunk (fp32 elements)
#define BLK 512     // 8 waves: 4 in M x 2 in N
#define NCHUNK (HID / KC)   // 12

typedef short bf16x8 __attribute__((ext_vector_type(8)));
typedef float f32x4  __attribute__((ext_vector_type(4)));

__device__ __forceinline__ unsigned short f2bf(float f) {
  union { float f; unsigned int u; } v; v.f = f;
  return (unsigned short)((v.u + 0x7FFFu + ((v.u >> 16) & 1u)) >> 16);
}

__device__ __forceinline__ void async_ld16(const void* g, void* l) {
  // global -> LDS DMA, 16 B per lane, dest = wave-uniform base + lane*16
  __builtin_amdgcn_global_load_lds(
      (const __attribute__((address_space(1))) unsigned int*)g,
      (__attribute__((address_space(3))) unsigned int*)l, 16, 0, 0);
}

// Fused: q[b,p] = (h[b,i0,:]+h[b,i1,:]).W[p,:] (fp32, per-block redundant),
// then out = sigmoid(h.W^T (bf16 MFMA) + bias + mask*q)^4
__global__ __launch_bounds__(BLK, 4) void fused_kernel(
    const float* __restrict__ h, const int* __restrict__ ids,
    const int* __restrict__ mask, const float* __restrict__ W,
    const float* __restrict__ bias, float* __restrict__ out) {

  // hA: fp32 H tile, [16 groups of 4 rows], each group 1024B data + 64B pad
  //     (pad de-aliases banks across the 4-row groups; gl_lds dest stays
  //      linear WITHIN each 1024B instruction footprint)
  // Within a row (256B = 8 chunks of 32B) chunks are XOR-swizzled by (row&7)
  // on the GLOBAL source side; reader applies the same XOR.
  __shared__ __align__(16) unsigned char  hA[2][16 * 1088];
  // wB: bf16 W tile [48 rows][128B]; 16B-chunk XOR swizzle by (row&7), write-side.
  __shared__ __align__(16) unsigned short wB[2][48][64];
  __shared__ float q_s[P2];

  const int tid  = threadIdx.x;
  const int lane = tid & 63, wv = tid >> 6;         // wv in [0,8)
  const int mr = lane & 15, qd = lane >> 4;
  const int wm = wv >> 1, wn = wv & 1;              // 4 M-waves x 2 N-waves
  const int row0 = blockIdx.x * MT;                 // flat row = b*SEQ + s
  const int b    = row0 >> 9;                       // SEQ = 512

  // ---- async H staging: 2 gl_lds per wave per chunk (4 rows x 256B each) ----
  auto stageH = [&](int c, int buf) {
    #pragma unroll
    for (int j2 = 0; j2 < 2; ++j2) {
      int j = (wv << 1) + j2;                       // group 0..15
      int r = (j << 2) + (lane >> 4);               // local row 0..63
      int gc = ((lane >> 1) & 7) ^ (r & 7);         // swizzled 32B chunk
      const float* src = h + (size_t)(row0 + r) * HID + (c << 6)
                           + (gc << 3) + ((lane & 1) << 2);
      async_ld16(src, &hA[buf][j * 1088]);
    }
  };

  // ---- W staging: reg -> bf16 -> swizzled ds_write (48x16 float4 = 768) ----
  auto stageW = [&](int c, int buf) {
    #pragma unroll
    for (int i = 0; i < 2; ++i) {
      int idx = tid + (i << 9);
      if (idx < 768) {
        int r = idx >> 4, c4 = idx & 15;
        float4 v = (r < P2)
            ? *(const float4*)(W + (size_t)r * HID + (c << 6) + (c4 << 2))
            : make_float4(0.f, 0.f, 0.f, 0.f);
        ushort4 u;
        u.x = f2bf(v.x); u.y = f2bf(v.y); u.z = f2bf(v.z); u.w = f2bf(v.w);
        int dst = (((c4 >> 1) ^ (r & 7)) << 3) + ((c4 & 1) << 2);
        *(ushort4*)&wB[buf][r][dst] = u;
      }
    }
  };

  f32x4 acc[2];
  acc[0] = f32x4{0.f, 0.f, 0.f, 0.f};
  acc[1] = f32x4{0.f, 0.f, 0.f, 0.f};

  auto compute = [&](int buf) {
    #pragma unroll
    for (int ks = 0; ks < 2; ++ks) {
      // A fragment: row = wm*16+mr, k = ks*32 + qd*8 + j  (fp32 -> bf16 here)
      int r  = (wm << 4) + mr;
      int cp = ((ks << 2) + qd) ^ (r & 7);
      const float4* ap =
          (const float4*)&hA[buf][(r >> 2) * 1088 + ((r & 3) << 8) + (cp << 5)];
      float4 a0 = ap[0], a1 = ap[1];
      bf16x8 a = { (short)f2bf(a0.x), (short)f2bf(a0.y),
                   (short)f2bf(a0.z), (short)f2bf(a0.w),
                   (short)f2bf(a1.x), (short)f2bf(a1.y),
                   (short)f2bf(a1.z), (short)f2bf(a1.w) };
      int bswz = (((ks << 2) + qd) ^ (mr & 7)) << 3;   // p&7 == mr&7 for all tiles
      {
        int p = (wn << 5) + mr;                        // cols 0..15 / 32..47
        bf16x8 bb = *(const bf16x8*)&wB[buf][p][bswz];
        acc[0] = __builtin_amdgcn_mfma_f32_16x16x32_bf16(a, bb, acc[0], 0, 0, 0);
      }
      if (!wn) {                                       // cols 16..31 (wave-uniform)
        bf16x8 bb = *(const bf16x8*)&wB[buf][16 + mr][bswz];
        acc[1] = __builtin_amdgcn_mfma_f32_16x16x32_bf16(a, bb, acc[1], 0, 0, 0);
      }
    }
  };

  // ---- prologue: kick chunk-0 prefetch, then compute q[b,:] in fp32 ----
  stageH(0, 0);
  stageW(0, 0);

  {
    const int i0 = ids[b * 2 + 0], i1 = ids[b * 2 + 1];
    const float* r0p = h + ((size_t)b * SEQ + i0) * HID;
    const float* r1p = h + ((size_t)b * SEQ + i1) * HID;
    for (int p = wv; p < P2; p += 8) {
      const float* wp = W + (size_t)p * HID;
      float a = 0.f;
      #pragma unroll
      for (int j = 0; j < HID / 64; ++j) {
        int k = lane + (j << 6);
        a += (r0p[k] + r1p[k]) * wp[k];
      }
      #pragma unroll
      for (int off = 32; off > 0; off >>= 1) a += __shfl_xor(a, off, 64);
      if (lane == 0) q_s[p] = a;
    }
  }
  __syncthreads();   // drains chunk-0 gl_lds (vmcnt 0) + W ds_writes

  // ---- main loop: issue next-chunk stage, compute current, barrier ----
  for (int c = 0; c < NCHUNK; ++c) {
    int buf = c & 1;
    if (c + 1 < NCHUNK) { stageH(c + 1, buf ^ 1); stageW(c + 1, buf ^ 1); }
    compute(buf);
    __syncthreads();
  }

  // ---- epilogue: C/D layout col = lane&15, row = qd*4 + reg ----
  const int rbase = row0 + (wm << 4) + (qd << 2);
  int msk[4];
  #pragma unroll
  for (int i = 0; i < 4; ++i) msk[i] = mask[rbase + i];

  auto storeNT = [&](f32x4 a, int p) {
    if (p < P2) {
      float bv = bias[p], qv = q_s[p];
      #pragma unroll
      for (int i = 0; i < 4; ++i) {
        float x = a[i] + bv + (msk[i] ? qv : 0.f);
        float sg = 1.f / (1.f + __expf(-x));
        sg *= sg; sg *= sg;               // sigmoid^4
        out[(size_t)(rbase + i) * P2 + p] = sg;
      }
    }
  };
  storeNT(acc[0], (wn << 5) + mr);
  if (!wn) storeNT(acc[1], 16 + mr);
}

extern "C" void kernel_launch(void* const* d_in, const int* in_sizes, int n_in,
                              void* d_out, int out_size, void* d_ws, size_t ws_size,
                              hipStream_t stream) {
  const float* h    = (const float*)d_in[0];   // [64,512,768] fp32
  const int*   ids  = (const int*)d_in[1];     // [64,2]
  const int*   mask = (const int*)d_in[2];     // [64,512]
  const float* W    = (const float*)d_in[3];   // [46,768]
  const float* bias = (const float*)d_in[4];   // [46]
  float* out = (float*)d_out;                  // [64,512,46] fp32

  fused_kernel<<<dim3((64 * SEQ) / MT), BLK, 0, stream>>>(h, ids, mask, W, bias, out);
}